// Round 3
// baseline (616.715 us; speedup 1.0000x reference)
//
#include <hip/hip_runtime.h>
#include <stdint.h>

// Problem constants (from reference): x[4,2048,4096] fp32, W[4096,4096] fp32,
// bias[4096] fp32, L[4096,16] fp32, R[16,4096] fp32. out = x @ (W + 2*L@R)^T + b.
#define NTOK     8192      // 4*2048 tokens (M)
#define D_OUT    4096      // N
#define D_IN     4096      // K
#define LORA_DIM 16
#define LORA_SCALE 2.0f    // 32.0 / 16

typedef short  short8  __attribute__((ext_vector_type(8)));   // 8 bf16 = 4 VGPRs (MFMA A/B frag)
typedef float  floatx4 __attribute__((ext_vector_type(4)));   // MFMA C/D frag
typedef unsigned short ushort4v __attribute__((ext_vector_type(4)));
typedef unsigned short ushort8v __attribute__((ext_vector_type(8)));

typedef unsigned int u32;
typedef __attribute__((address_space(3))) u32 lds_u32;
typedef __attribute__((address_space(1))) u32 glb_u32;

// fp32 -> bf16 round-to-nearest-even
__device__ __forceinline__ unsigned short f2bf(float f) {
  unsigned int u = __builtin_bit_cast(unsigned int, f);
  u += 0x7FFFu + ((u >> 16) & 1u);
  return (unsigned short)(u >> 16);
}

// async global->LDS, 16B per lane. LDS dest must be wave-uniform base + lane*16.
__device__ __forceinline__ void copy16(const void* g, void* l) {
  __builtin_amdgcn_global_load_lds((glb_u32*)(uintptr_t)g, (lds_u32*)(uintptr_t)l,
                                   16, 0, 0);
}

// ---------------------------------------------------------------------------
// Kernel 1: x (fp32) -> bf16, 8 elems/thread (2x float4 in, 1x 16B out)
// ---------------------------------------------------------------------------
__global__ __launch_bounds__(256) void cvt_x(const float* __restrict__ X,
                                             unsigned short* __restrict__ Xb) {
  const size_t i = ((size_t)blockIdx.x * 256 + threadIdx.x) * 8;
  const float4 v0 = *(const float4*)(X + i);
  const float4 v1 = *(const float4*)(X + i + 4);
  ushort8v o;
  o[0] = f2bf(v0.x); o[1] = f2bf(v0.y); o[2] = f2bf(v0.z); o[3] = f2bf(v0.w);
  o[4] = f2bf(v1.x); o[5] = f2bf(v1.y); o[6] = f2bf(v1.z); o[7] = f2bf(v1.w);
  *(ushort8v*)(Xb + i) = o;
}

// ---------------------------------------------------------------------------
// Kernel 2: W_eff = W + 2*(L@R), cast to bf16. One block per output row o.
// ---------------------------------------------------------------------------
__global__ __launch_bounds__(256) void make_weff(const float* __restrict__ W,
                                                 const float* __restrict__ L,
                                                 const float* __restrict__ R,
                                                 unsigned short* __restrict__ Wb) {
  const int o = blockIdx.x;
  const int tid = threadIdx.x;
  float l[LORA_DIM];
#pragma unroll
  for (int d = 0; d < LORA_DIM; ++d) l[d] = LORA_SCALE * L[o * LORA_DIM + d];
  for (int i = tid * 4; i < D_IN; i += 256 * 4) {
    const float4 w = *(const float4*)(W + (size_t)o * D_IN + i);
    float a0 = w.x, a1 = w.y, a2 = w.z, a3 = w.w;
#pragma unroll
    for (int d = 0; d < LORA_DIM; ++d) {
      const float4 r = *(const float4*)(R + (size_t)d * D_IN + i);
      a0 += l[d] * r.x; a1 += l[d] * r.y; a2 += l[d] * r.z; a3 += l[d] * r.w;
    }
    ushort4v ov;
    ov.x = f2bf(a0); ov.y = f2bf(a1); ov.z = f2bf(a2); ov.w = f2bf(a3);
    *(ushort4v*)(Wb + (size_t)o * D_IN + i) = ov;
  }
}

// ---------------------------------------------------------------------------
// Kernel 3: C[M,N] = A[M,K](bf16) * B[N,K](bf16)^T + bias, fp32 out.
// BK=64 variant: 64 K-iters (vs 128) -> half the barrier-drain events,
// 32 MFMA per wave per barrier-pair (AITER-like density). LDS 2x16 KB.
// XOR swizzle for 8-chunk rows: 16B chunk c of row r stored at phys chunk
// c ^ (r&7) -> fragment reads spread 16 lanes over all 8 bank-groups
// (2-way aliasing = free). global_load_lds dest stays tid-linear (required).
// ---------------------------------------------------------------------------
#define BM 128
#define BN 128
#define BK 64

__global__ __launch_bounds__(256) void gemm_bt(
    const unsigned short* __restrict__ A,   // [NTOK, D_IN] bf16
    const unsigned short* __restrict__ B,   // [D_OUT, D_IN] bf16 (W_eff)
    const float* __restrict__ bias,
    float* __restrict__ C) {                // [NTOK, D_OUT] fp32
  __shared__ __align__(16) unsigned short sA[BM * BK];  // 16 KB
  __shared__ __align__(16) unsigned short sB[BN * BK];  // 16 KB

  const int tid = threadIdx.x;
  const int m0 = blockIdx.y * BM;
  const int n0 = blockIdx.x * BN;

  // Staging: 4 copy16 per thread per tile. Chunk index c = i*256 + tid,
  // LDS byte offset c*16; row = c>>3 = (tid>>3) + 32*i, phys chunk p = tid&7.
  // Logical (global) chunk l = p ^ (row&7) = p ^ ((tid>>3)&7)  (32*i === 0 mod 8).
  const int r0 = tid >> 3;                       // 0..31
  const int p  = tid & 7;
  const int l  = p ^ (r0 & 7);
  const unsigned short* gA[4];
  const unsigned short* gB[4];
  unsigned short* lA[4];
  unsigned short* lB[4];
#pragma unroll
  for (int i = 0; i < 4; ++i) {
    const int row = r0 + 32 * i;
    gA[i] = A + (size_t)(m0 + row) * D_IN + l * 8;
    gB[i] = B + (size_t)(n0 + row) * D_IN + l * 8;
    lA[i] = &sA[row * BK + p * 8];
    lB[i] = &sB[row * BK + p * 8];
  }

  // Fragment map (mfma_f32_16x16x32_bf16):
  //  A operand: lane holds A[m=lane&15][k=(lane>>4)*8 + j]
  //  B operand: lane holds Bt[n=lane&15][k=(lane>>4)*8 + j]
  const int lane = tid & 63;
  const int w  = tid >> 6;
  const int wm = (w >> 1) * 64;     // wave's 64x64 subtile origin
  const int wn = (w & 1) * 64;
  const int fr = lane & 15;
  const int q  = lane >> 4;
  // k-step s covers tile-k [32s,32s+32): logical chunk = s*4 + q,
  // phys chunk = (s*4+q) ^ (row&7); row&7 == fr&7 (wm, t*16 === 0 mod 8... t*16 mod 8 == 0).
  const int fx = fr & 7;
  const int fk0 = ((0 * 4 + q) ^ fx) * 8;   // element offset in row, k-step 0
  const int fk1 = ((1 * 4 + q) ^ fx) * 8;   // k-step 1

  floatx4 acc[4][4] = {};

  for (int k0 = 0; k0 < D_IN; k0 += BK) {
#pragma unroll
    for (int i = 0; i < 4; ++i) copy16(gA[i] + k0, lA[i]);
#pragma unroll
    for (int i = 0; i < 4; ++i) copy16(gB[i] + k0, lB[i]);
    __syncthreads();                // drains vmcnt(0) then barrier

    // k-step 0
    {
      short8 av[4], bv[4];
#pragma unroll
      for (int t = 0; t < 4; ++t) {
        av[t] = *(const short8*)&sA[(wm + t * 16 + fr) * BK + fk0];
        bv[t] = *(const short8*)&sB[(wn + t * 16 + fr) * BK + fk0];
      }
#pragma unroll
      for (int i = 0; i < 4; ++i)
#pragma unroll
        for (int j = 0; j < 4; ++j)
          acc[i][j] = __builtin_amdgcn_mfma_f32_16x16x32_bf16(av[i], bv[j],
                                                              acc[i][j], 0, 0, 0);
    }
    // k-step 1
    {
      short8 av[4], bv[4];
#pragma unroll
      for (int t = 0; t < 4; ++t) {
        av[t] = *(const short8*)&sA[(wm + t * 16 + fr) * BK + fk1];
        bv[t] = *(const short8*)&sB[(wn + t * 16 + fr) * BK + fk1];
      }
#pragma unroll
      for (int i = 0; i < 4; ++i)
#pragma unroll
        for (int j = 0; j < 4; ++j)
          acc[i][j] = __builtin_amdgcn_mfma_f32_16x16x32_bf16(av[i], bv[j],
                                                              acc[i][j], 0, 0, 0);
    }
    __syncthreads();                // protect LDS before next stage
  }

  // C/D layout: col = lane&15, row = (lane>>4)*4 + reg (m89/m91-verified)
  const int qr = q * 4;
#pragma unroll
  for (int i = 0; i < 4; ++i) {
    const int row = m0 + wm + i * 16 + qr;
#pragma unroll
    for (int j = 0; j < 4; ++j) {
      const int col = n0 + wn + j * 16 + fr;
      const float bs = bias[col];
      const floatx4 v = acc[i][j];
#pragma unroll
      for (int r = 0; r < 4; ++r)
        C[(size_t)(row + r) * D_OUT + col] = v[r] + bs;
    }
  }
}

// ---------------------------------------------------------------------------
extern "C" void kernel_launch(void* const* d_in, const int* in_sizes, int n_in,
                              void* d_out, int out_size, void* d_ws, size_t ws_size,
                              hipStream_t stream) {
  const float* x    = (const float*)d_in[0];
  const float* W    = (const float*)d_in[1];
  const float* bias = (const float*)d_in[2];
  const float* L    = (const float*)d_in[3];
  const float* R    = (const float*)d_in[4];
  float* out = (float*)d_out;

  // Workspace layout: x_bf16 (64 MB) | W_eff bf16 (32 MB)
  const size_t need = ((size_t)NTOK * D_IN + (size_t)D_OUT * D_IN) * sizeof(unsigned short);
  if (ws_size < need) return;  // fail cleanly (all-zero out) rather than corrupt

  unsigned short* xb = (unsigned short*)d_ws;
  unsigned short* wb = xb + (size_t)NTOK * D_IN;

  cvt_x<<<((size_t)NTOK * D_IN) / (256 * 8), 256, 0, stream>>>(x, xb);
  make_weff<<<D_OUT, 256, 0, stream>>>(W, L, R, wb);
  gemm_bt<<<dim3(D_OUT / BN, NTOK / BM), 256, 0, stream>>>(xb, wb, bias, out);
}